// Round 6
// baseline (116.334 us; speedup 1.0000x reference)
//
#include <hip/hip_runtime.h>
#include <hip/hip_bf16.h>
#include <stdint.h>

// SimCLR loss, B=4096, D=256, T=0.1.
// loss = (1/2B) * sum_i [ log(sum_{j!=i} exp(sim_ij)) - sim_{i,pair(i)} ]
// sim in [-10,10] => no max-subtraction needed.
// Gram in FP8 e4m3 (positive-pair term exact fp32). Full K=256 row = 256 B:
// a 128x128 tile stages A+B = 64 KB LDS in ONE shot, one barrier per tile.
// KEY CHANGE (R6): zn8 is stored PRE-SWIZZLED in global memory (granule
// slot = k16 ^ (row&15), an involution) so global_load_lds uses contiguous
// lane*16 addresses (coalesced 1KB/instr DMA, m97-style) instead of a
// 64-lane gather, while ds_read stays bank-conflict-free.
// Symmetric: lower-triangle tiles only (2080); off-diag tiles add row sums
// to rowsum[i] and col sums to rowsum[j].

#define BROWS 4096
#define NROWS 8192
#define DDIM  256
#define TINV  10.0f
#define EPSN  1e-8f

#define TM    128
#define NTILE (NROWS / TM)               // 64
#define NTRI  (NTILE * (NTILE + 1) / 2)  // 2080

typedef float f32x4 __attribute__((ext_vector_type(4)));

// ------- prep: norms + fp8 unit rows (pre-swizzled) + pos + zeroing -------
__global__ __launch_bounds__(256) void prep_kernel(
    const float* __restrict__ z1, const float* __restrict__ z2,
    unsigned int* __restrict__ zn8, float* __restrict__ pos,
    float* __restrict__ rowsum, float* __restrict__ out) {
  int t = threadIdx.x;
  int i    = blockIdx.x * 4 + (t >> 6);
  int lane = t & 63;
  if (blockIdx.x < 32) rowsum[blockIdx.x * 256 + t] = 0.f;
  if (blockIdx.x == 32 && t == 0) out[0] = 0.f;

  float4 a = ((const float4*)(z1 + (size_t)i * DDIM))[lane];
  float4 b = ((const float4*)(z2 + (size_t)i * DDIM))[lane];
  float s1 = a.x*a.x + a.y*a.y + a.z*a.z + a.w*a.w;
  float s2 = b.x*b.x + b.y*b.y + b.z*b.z + b.w*b.w;
  float dt = a.x*b.x + a.y*b.y + a.z*b.z + a.w*b.w;
  #pragma unroll
  for (int off = 32; off; off >>= 1) {
    s1 += __shfl_xor(s1, off, 64);
    s2 += __shfl_xor(s2, off, 64);
    dt += __shfl_xor(dt, off, 64);
  }
  float i1 = 1.0f / fmaxf(sqrtf(s1), EPSN);
  float i2 = 1.0f / fmaxf(sqrtf(s2), EPSN);
  if (lane == 0) pos[i] = dt * i1 * i2 * TINV;
  // pack 4 normalized floats -> 4 fp8 e4m3 bytes (one dword per lane)
  int p1 = __builtin_amdgcn_cvt_pk_fp8_f32(a.x*i1, a.y*i1, 0, false);
  p1     = __builtin_amdgcn_cvt_pk_fp8_f32(a.z*i1, a.w*i1, p1, true);
  int p2 = __builtin_amdgcn_cvt_pk_fp8_f32(b.x*i2, b.y*i2, 0, false);
  p2     = __builtin_amdgcn_cvt_pk_fp8_f32(b.z*i2, b.w*i2, p2, true);
  // lane holds dword (k-bytes lane*4..+4) = granule g16 = lane>>2, b4 = lane&3.
  // store granule g16 at slot g16 ^ (row&15).  (BROWS % 16 == 0 -> same key)
  int g16 = lane >> 2, b4 = lane & 3;
  int slot = g16 ^ (i & 15);
  zn8[(size_t)i * 64 + slot * 4 + b4]             = (unsigned int)p1;
  zn8[(size_t)(i + BROWS) * 64 + slot * 4 + b4]   = (unsigned int)p2;
}

// ---------------- async global->LDS, 16B (contiguous, coalesced) ----------
__device__ __forceinline__ void async16(const unsigned char* g, unsigned char* l) {
  __builtin_amdgcn_global_load_lds(
      (const __attribute__((address_space(1))) unsigned int*)g,
      (__attribute__((address_space(3))) unsigned int*)l,
      16, 0, 0);
}

__device__ __forceinline__ void decode_tri(int tid, int& bi, int& bj) {
  int x = (int)((sqrtf(8.0f * tid + 1.0f) - 1.0f) * 0.5f);
  while ((x + 1) * (x + 2) / 2 <= tid) ++x;
  while (x * (x + 1) / 2 > tid) --x;
  bi = x; bj = tid - x * (x + 1) / 2;
}

// ---------------- one-shot fp8 Gram tile + exp + row/col sums --------------
__global__ __launch_bounds__(256) void simexp_kernel(
    const unsigned char* __restrict__ zn8, float* __restrict__ rowsum) {
  __shared__ __align__(16) unsigned char ldsA[TM * 256];   // 32 KB
  __shared__ __align__(16) unsigned char ldsB[TM * 256];   // 32 KB

  int bi, bj;
  decode_tri(blockIdx.x, bi, bj);

  const int t = threadIdx.x;
  const int wave = t >> 6, lane = t & 63;
  const int wr = wave >> 1, wc = wave & 1;
  const int quad = lane >> 4, l15 = lane & 15;
  const int rowA0 = bi * TM, rowB0 = bj * TM;

  // ---- stage whole tile pair: plain contiguous copy (global pre-swizzled)
  const unsigned char* baseA = zn8 + (size_t)rowA0 * 256;
  const unsigned char* baseB = zn8 + (size_t)rowB0 * 256;
  #pragma unroll
  for (int p = 0; p < 8; ++p) {
    int j = p * 256 + t;                  // 16B granule index 0..2047
    async16(baseA + (size_t)j * 16, &ldsA[j * 16]);
    async16(baseB + (size_t)j * 16, &ldsB[j * 16]);
  }
  __syncthreads();                        // the ONLY barrier

  // ---- full-K MFMA: 8 k-steps x 4x4 frags = 128 MFMA per wave -----------
  f32x4 acc[4][4] = {};
  #pragma unroll
  for (int ks = 0; ks < 8; ++ks) {
    // lane wants k-bytes [ks*32 + quad*8 .. +8) = granule ks*2 + (quad>>1),
    // stored at LDS slot granule ^ (row&15); sub-offset (quad&1)*8
    const int gr  = ks * 2 + (quad >> 1);
    const int sub = (quad & 1) * 8;
    long af[4], bg[4];
    #pragma unroll
    for (int mi = 0; mi < 4; ++mi) {
      int row = wr * 64 + mi * 16 + l15;
      af[mi] = *(const long*)&ldsA[row * 256 + ((gr ^ (row & 15)) * 16) + sub];
    }
    #pragma unroll
    for (int nj = 0; nj < 4; ++nj) {
      int row = wc * 64 + nj * 16 + l15;
      bg[nj] = *(const long*)&ldsB[row * 256 + ((gr ^ (row & 15)) * 16) + sub];
    }
    #pragma unroll
    for (int mi = 0; mi < 4; ++mi)
      #pragma unroll
      for (int nj = 0; nj < 4; ++nj)
        acc[mi][nj] = __builtin_amdgcn_mfma_f32_16x16x32_fp8_fp8(
            af[mi], bg[nj], acc[mi][nj], 0, 0, 0);
  }

  // ---- epilogue: exp (diag masked), row sums + (off-diag) col sums ------
  float cs[4] = {0.f, 0.f, 0.f, 0.f};
  #pragma unroll
  for (int mi = 0; mi < 4; ++mi) {
    float rs[4] = {0.f, 0.f, 0.f, 0.f};
    #pragma unroll
    for (int nj = 0; nj < 4; ++nj) {
      int gj = rowB0 + wc * 64 + nj * 16 + l15;
      #pragma unroll
      for (int r = 0; r < 4; ++r) {
        int gi = rowA0 + wr * 64 + mi * 16 + quad * 4 + r;
        float e = (gi == gj) ? 0.f : __expf(acc[mi][nj][r] * TINV);
        rs[r] += e;
        cs[nj] += e;
      }
    }
    #pragma unroll
    for (int r = 0; r < 4; ++r) {
      float v = rs[r];
      v += __shfl_xor(v, 1, 64);
      v += __shfl_xor(v, 2, 64);
      v += __shfl_xor(v, 4, 64);
      v += __shfl_xor(v, 8, 64);
      if (l15 == 0)
        atomicAdd(&rowsum[rowA0 + wr * 64 + mi * 16 + quad * 4 + r], v);
    }
  }
  if (bi != bj) {
    #pragma unroll
    for (int nj = 0; nj < 4; ++nj) {
      float v = cs[nj];
      v += __shfl_xor(v, 16, 64);
      v += __shfl_xor(v, 32, 64);
      if (quad == 0)
        atomicAdd(&rowsum[rowB0 + wc * 64 + nj * 16 + l15], v);
    }
  }
}

// ---------------- final scalar reduction (32 blocks) -----------------------
__global__ __launch_bounds__(256) void finalize_kernel(
    const float* __restrict__ rowsum, const float* __restrict__ pos,
    float* __restrict__ out) {
  __shared__ float red[4];
  int t = threadIdx.x;
  int idx = blockIdx.x * 256 + t;
  float s = __logf(rowsum[idx]);
  if (idx < BROWS) s -= 2.f * pos[idx];
  #pragma unroll
  for (int off = 32; off; off >>= 1) s += __shfl_xor(s, off, 64);
  if ((t & 63) == 0) red[t >> 6] = s;
  __syncthreads();
  if (t == 0)
    atomicAdd(out, (red[0] + red[1] + red[2] + red[3]) / (float)NROWS);
}

// ---------------- launch ----------------------------------------------------
extern "C" void kernel_launch(void* const* d_in, const int* in_sizes, int n_in,
                              void* d_out, int out_size, void* d_ws, size_t ws_size,
                              hipStream_t stream) {
  const float* z1 = (const float*)d_in[0];
  const float* z2 = (const float*)d_in[1];
  char* ws = (char*)d_ws;
  unsigned int* zn8 = (unsigned int*)ws;                   // 2 MB (fp8 rows)
  float* rowsum = (float*)(ws + 2097152);                  // 32 KB
  float* pos    = (float*)(ws + 2097152 + 32768);          // 16 KB
  float* out    = (float*)d_out;

  prep_kernel<<<BROWS / 4, 256, 0, stream>>>(z1, z2, zn8, pos, rowsum, out);
  simexp_kernel<<<NTRI, 256, 0, stream>>>((const unsigned char*)zn8, rowsum);
  finalize_kernel<<<NROWS / 256, 256, 0, stream>>>(rowsum, pos, out);
}

// Round 7
// 92.931 us; speedup vs baseline: 1.2518x; 1.2518x over previous
//
#include <hip/hip_runtime.h>
#include <hip/hip_bf16.h>
#include <stdint.h>

// SimCLR loss, B=4096, D=256, T=0.1.
// loss = (1/2B) * sum_i [ log(sum_{j!=i} exp(sim_ij)) - sim_{i,pair(i)} ]
// sim in [-10,10] => no max-subtraction needed.
// R7: MX-scaled fp8 MFMA (16x16x128, scales=1.0) -> 2x MFMA rate AND
// conflict-free b128 LDS fragment reads. A strip resident in VGPRs.
// 544 strip blocks (<=4 consecutive same-bi tiles), B double-buffered
// (2x32KB LDS; A borrows buf1 before the B stream starts).
// Symmetric: lower-triangle tiles; off-diag adds row sums AND col sums.

#define BROWS 4096
#define NROWS 8192
#define DDIM  256
#define TINV  10.0f
#define LOG2E10 14.4269504088896340736f   // 10 * log2(e)
#define EPSN  1e-8f

#define TM    128
#define NTILE (NROWS / TM)               // 64
#define NBLK  544                        // sum_{m=1..64} ceil(m/4)

typedef float f32x4 __attribute__((ext_vector_type(4)));
typedef int   i32x4 __attribute__((ext_vector_type(4)));
typedef int   i32x8 __attribute__((ext_vector_type(8)));

// ------- prep: norms + fp8 unit rows (pre-swizzled) + pos + zeroing -------
// row image: 16 granules of 16B; granule g stored at slot g ^ (row&15).
__global__ __launch_bounds__(256) void prep_kernel(
    const float* __restrict__ z1, const float* __restrict__ z2,
    unsigned int* __restrict__ zn8, float* __restrict__ pos,
    float* __restrict__ rowsum, float* __restrict__ out) {
  int t = threadIdx.x;
  int i    = blockIdx.x * 4 + (t >> 6);
  int lane = t & 63;
  if (blockIdx.x < 32) rowsum[blockIdx.x * 256 + t] = 0.f;
  if (blockIdx.x == 32 && t == 0) out[0] = 0.f;

  float4 a = ((const float4*)(z1 + (size_t)i * DDIM))[lane];
  float4 b = ((const float4*)(z2 + (size_t)i * DDIM))[lane];
  float s1 = a.x*a.x + a.y*a.y + a.z*a.z + a.w*a.w;
  float s2 = b.x*b.x + b.y*b.y + b.z*b.z + b.w*b.w;
  float dt = a.x*b.x + a.y*b.y + a.z*b.z + a.w*b.w;
  #pragma unroll
  for (int off = 32; off; off >>= 1) {
    s1 += __shfl_xor(s1, off, 64);
    s2 += __shfl_xor(s2, off, 64);
    dt += __shfl_xor(dt, off, 64);
  }
  float i1 = 1.0f / fmaxf(sqrtf(s1), EPSN);
  float i2 = 1.0f / fmaxf(sqrtf(s2), EPSN);
  if (lane == 0) pos[i] = dt * i1 * i2 * TINV;
  int p1 = __builtin_amdgcn_cvt_pk_fp8_f32(a.x*i1, a.y*i1, 0, false);
  p1     = __builtin_amdgcn_cvt_pk_fp8_f32(a.z*i1, a.w*i1, p1, true);
  int p2 = __builtin_amdgcn_cvt_pk_fp8_f32(b.x*i2, b.y*i2, 0, false);
  p2     = __builtin_amdgcn_cvt_pk_fp8_f32(b.z*i2, b.w*i2, p2, true);
  int g16 = lane >> 2, b4 = lane & 3;
  int slot = g16 ^ (i & 15);                 // (i+BROWS)&15 == i&15
  zn8[(size_t)i * 64 + slot * 4 + b4]           = (unsigned int)p1;
  zn8[(size_t)(i + BROWS) * 64 + slot * 4 + b4] = (unsigned int)p2;
}

// ---------------- async global->LDS, 16B (contiguous) ----------------------
__device__ __forceinline__ void async16(const unsigned char* g, unsigned char* l) {
  __builtin_amdgcn_global_load_lds(
      (const __attribute__((address_space(1))) unsigned int*)g,
      (__attribute__((address_space(3))) unsigned int*)l,
      16, 0, 0);
}

// ---------------- strip Gram + exp + row/col sums --------------------------
__global__ __launch_bounds__(256, 2) void simexp_kernel(
    const unsigned char* __restrict__ zn8, float* __restrict__ rowsum) {
  __shared__ __align__(16) unsigned char lds[2][TM * 256];  // 2 x 32 KB

  // block -> (bi, bj0, nt): row bi has ceil((bi+1)/4) groups of <=4 tiles
  int b = blockIdx.x;
  int bi = 0, cum = 0;
  for (;;) { int ng = (bi + 4) >> 2; if (cum + ng > b) break; cum += ng; ++bi; }
  const int bj0 = (b - cum) * 4;
  const int nt  = min(bi - bj0 + 1, 4);

  const int t = threadIdx.x;
  const int wave = t >> 6, lane = t & 63;
  const int wr = wave >> 1, wc = wave & 1;
  const int quad = lane >> 4, l15 = lane & 15;
  const int rowA0 = bi * TM;

  auto stage = [&](const unsigned char* gbase, int buf) {
    #pragma unroll
    for (int p = 0; p < 8; ++p) {
      int j = p * 256 + t;
      async16(gbase + (size_t)j * 16, &lds[buf][j * 16]);
    }
  };

  // stage A -> buf1, B0 -> buf0
  stage(zn8 + (size_t)rowA0 * 256, 1);
  stage(zn8 + (size_t)(bj0 * TM) * 256, 0);
  __syncthreads();

  // extract A fragments to VGPRs: afr[mi][kb] = 32 k-bytes of row
  // (rowA0 + wr*64 + mi*16 + l15), k in [kb*128 + quad*32, +32)
  i32x8 afr[4][2];
  #pragma unroll
  for (int mi = 0; mi < 4; ++mi) {
    int row = wr * 64 + mi * 16 + l15;
    const unsigned char* rbase = &lds[1][row * 256];
    #pragma unroll
    for (int kb = 0; kb < 2; ++kb) {
      int g0 = kb * 8 + quad * 2;
      i32x4 lo = *(const i32x4*)(rbase + ((g0 ^ (row & 15)) << 4));
      i32x4 hi = *(const i32x4*)(rbase + (((g0 + 1) ^ (row & 15)) << 4));
      afr[mi][kb][0] = lo[0]; afr[mi][kb][1] = lo[1];
      afr[mi][kb][2] = lo[2]; afr[mi][kb][3] = lo[3];
      afr[mi][kb][4] = hi[0]; afr[mi][kb][5] = hi[1];
      afr[mi][kb][6] = hi[2]; afr[mi][kb][7] = hi[3];
    }
  }
  __syncthreads();                       // buf1 free before B1 DMA
  if (nt > 1) stage(zn8 + (size_t)((bj0 + 1) * TM) * 256, 1);

  float rs[4][4] = {};                   // strip row sums (regs)

  for (int tix = 0; tix < nt; ++tix) {
    const unsigned char* bb = lds[tix & 1];
    const int bj = bj0 + tix, rowB0 = bj * TM;

    f32x4 acc[4][4] = {};
    #pragma unroll
    for (int kb = 0; kb < 2; ++kb) {
      i32x8 bfr[4];
      #pragma unroll
      for (int nj = 0; nj < 4; ++nj) {
        int row = wc * 64 + nj * 16 + l15;
        const unsigned char* rbase = bb + row * 256;
        int g0 = kb * 8 + quad * 2;
        i32x4 lo = *(const i32x4*)(rbase + ((g0 ^ (row & 15)) << 4));
        i32x4 hi = *(const i32x4*)(rbase + (((g0 + 1) ^ (row & 15)) << 4));
        bfr[nj][0] = lo[0]; bfr[nj][1] = lo[1];
        bfr[nj][2] = lo[2]; bfr[nj][3] = lo[3];
        bfr[nj][4] = hi[0]; bfr[nj][5] = hi[1];
        bfr[nj][6] = hi[2]; bfr[nj][7] = hi[3];
      }
      #pragma unroll
      for (int mi = 0; mi < 4; ++mi)
        #pragma unroll
        for (int nj = 0; nj < 4; ++nj)
          acc[mi][nj] = __builtin_amdgcn_mfma_scale_f32_16x16x128_f8f6f4(
              afr[mi][kb], bfr[nj], acc[mi][nj],
              0, 0,                       // cbsz=fp8(e4m3), blgp=fp8(e4m3)
              0, 0x7F7F7F7F,              // scale_a opsel, scale_a = 1.0
              0, 0x7F7F7F7F);             // scale_b opsel, scale_b = 1.0
    }

    // epilogue: exp2(acc * 10*log2e); diag mask only on the diagonal tile
    float cs[4] = {0.f, 0.f, 0.f, 0.f};
    if (bj == bi) {
      #pragma unroll
      for (int mi = 0; mi < 4; ++mi)
        #pragma unroll
        for (int nj = 0; nj < 4; ++nj) {
          int gj = wc * 64 + nj * 16 + l15;            // tile-local col
          #pragma unroll
          for (int r = 0; r < 4; ++r) {
            int gi = wr * 64 + mi * 16 + quad * 4 + r; // tile-local row
            float e = (gi == gj) ? 0.f : exp2f(acc[mi][nj][r] * LOG2E10);
            rs[mi][r] += e;
            cs[nj] += e;
          }
        }
    } else {
      #pragma unroll
      for (int mi = 0; mi < 4; ++mi)
        #pragma unroll
        for (int nj = 0; nj < 4; ++nj)
          #pragma unroll
          for (int r = 0; r < 4; ++r) {
            float e = exp2f(acc[mi][nj][r] * LOG2E10);
            rs[mi][r] += e;
            cs[nj] += e;
          }
      // symmetry: column sums -> rowsum[gj]
      #pragma unroll
      for (int nj = 0; nj < 4; ++nj) {
        float v = cs[nj];
        v += __shfl_xor(v, 16, 64);
        v += __shfl_xor(v, 32, 64);
        if (quad == 0)
          atomicAdd(&rowsum[rowB0 + wc * 64 + nj * 16 + l15], v);
      }
    }

    if (tix + 1 < nt) {
      __syncthreads();                   // drains B_{t+1}; frees buf[tix&1]
      if (tix + 2 < nt)
        stage(zn8 + (size_t)((bj0 + tix + 2) * TM) * 256, tix & 1);
    }
  }

  // strip row sums -> one atomic per (row, wave-half)
  #pragma unroll
  for (int mi = 0; mi < 4; ++mi)
    #pragma unroll
    for (int r = 0; r < 4; ++r) {
      float v = rs[mi][r];
      v += __shfl_xor(v, 1, 64);
      v += __shfl_xor(v, 2, 64);
      v += __shfl_xor(v, 4, 64);
      v += __shfl_xor(v, 8, 64);
      if (l15 == 0)
        atomicAdd(&rowsum[rowA0 + wr * 64 + mi * 16 + quad * 4 + r], v);
    }
}

// ---------------- final scalar reduction (32 blocks) -----------------------
__global__ __launch_bounds__(256) void finalize_kernel(
    const float* __restrict__ rowsum, const float* __restrict__ pos,
    float* __restrict__ out) {
  __shared__ float red[4];
  int t = threadIdx.x;
  int idx = blockIdx.x * 256 + t;
  float s = __logf(rowsum[idx]);
  if (idx < BROWS) s -= 2.f * pos[idx];
  #pragma unroll
  for (int off = 32; off; off >>= 1) s += __shfl_xor(s, off, 64);
  if ((t & 63) == 0) red[t >> 6] = s;
  __syncthreads();
  if (t == 0)
    atomicAdd(out, (red[0] + red[1] + red[2] + red[3]) / (float)NROWS);
}

// ---------------- launch ----------------------------------------------------
extern "C" void kernel_launch(void* const* d_in, const int* in_sizes, int n_in,
                              void* d_out, int out_size, void* d_ws, size_t ws_size,
                              hipStream_t stream) {
  const float* z1 = (const float*)d_in[0];
  const float* z2 = (const float*)d_in[1];
  char* ws = (char*)d_ws;
  unsigned int* zn8 = (unsigned int*)ws;                   // 2 MB (fp8 rows)
  float* rowsum = (float*)(ws + 2097152);                  // 32 KB
  float* pos    = (float*)(ws + 2097152 + 32768);          // 16 KB
  float* out    = (float*)d_out;

  prep_kernel<<<BROWS / 4, 256, 0, stream>>>(z1, z2, zn8, pos, rowsum, out);
  simexp_kernel<<<NBLK, 256, 0, stream>>>((const unsigned char*)zn8, rowsum);
  finalize_kernel<<<NROWS / 256, 256, 0, stream>>>(rowsum, pos, out);
}